// Round 2
// baseline (858.981 us; speedup 1.0000x reference)
//
#include <hip/hip_runtime.h>

// ============================================================================
// Fully-fused 3-layer Elman RNN, *** FP32 in/out ***, MFMA 16x16x32 bf16 via
// Ootomo 3-term double-bf16 products (ah*bh + ah*bl + al*bh, err ~2^-18).
//   B=8192, T=64, dims: 84 -> 128 -> 128 -> 84
// R5 change (barrier-shadow prefetch): R4 counters: 2 waves/SIMD (reg-locked:
// 176 weight regs -> no 3rd wave), LDS pipe ~11-12k cy/step busy of 17.4k
// total -> ~5k stall gap. __syncthreads drains lgkmcnt(0), so every barrier
// exposes a cold ds_read ramp (~120cy) while the pre-barrier epilogue leaves
// the LDS pipe idle. Fix, precision untouched:
//   - Prefetch the first 2 K-chunks of each layer's RECURRENCE A-frags
//     (stable parity plane: h1[p] pre-b1, h2[p] pre-b2, next-t h0[pn] during
//     L2) into 32 regs BEFORE the barrier; consume them as the FIRST MFMAs
//     after the barrier (accumulation commutes). Demand-load the rest.
//   - s_setprio(1) around the pure-register prefetch-MFMA cluster (T5).
//   - Prefetch depth 2 chunks keeps total regs ~250 < 256 (2 waves/SIMD).
// Hazard audit (delta over R3/R4 audit): h1[p] last written before b2(t-1) <
// b1(t) read; h2[p] written after b2(t-1), read after b1(t) -> separated;
// h0[pn] stable since b1(t), concurrent L0(t+1) writers (waves 3,7 racing
// ahead) hit h0[p] = other parity. All reads/writes separated by >=1 barrier.
// Numerics: NO precision change (absmax 2^-8 implies ~400x recurrence error
// amplification; single-bf16 anywhere would fail the 2% threshold).
// ============================================================================

typedef __bf16 bf16x8 __attribute__((ext_vector_type(8)));
typedef float  f32x4  __attribute__((ext_vector_type(4)));
typedef unsigned short u16;
typedef unsigned int   u32;
typedef u16 u16x8 __attribute__((ext_vector_type(8)));

#define MFMA16(a, b, c) __builtin_amdgcn_mfma_f32_16x16x32_bf16((a), (b), (c), 0, 0, 0)

__device__ __forceinline__ float bf2f(u16 v) {
    return __builtin_bit_cast(float, (u32)v << 16);
}
// float -> bf16 round-to-nearest-even (finite inputs only)
__device__ __forceinline__ u16 f2bf(float f) {
    u32 u = __builtin_bit_cast(u32, f);
    u = u + 0x7fffu + ((u >> 16) & 1u);
    return (u16)(u >> 16);
}
__device__ __forceinline__ float tanh_fast(float x) {
    float xc = fminf(fmaxf(x, -12.f), 12.f);           // avoid inf/inf
    float e  = __expf(2.f * xc);
    return (e - 1.f) * __builtin_amdgcn_rcpf(e + 1.f); // ~1e-7 rel err
}
__device__ __forceinline__ f32x4 splat4(float v) {
    f32x4 r; r[0] = v; r[1] = v; r[2] = v; r[3] = v; return r;
}
__device__ __forceinline__ bf16x8 ld_lds8(const u16* p) {
    return __builtin_bit_cast(bf16x8, *(const u16x8*)p);
}
__device__ __forceinline__ bf16x8 zero8() {
    u16x8 z = {0,0,0,0,0,0,0,0};
    return __builtin_bit_cast(bf16x8, z);
}
// split fp32 into hi+lo bf16 (v - hi exact in fp32; residual ~2^-18 * |v|)
__device__ __forceinline__ void store_hl(u16* ph, u16* pl, float v) {
    u16 hi = f2bf(v);
    *ph = hi;
    *pl = f2bf(v - bf2f(hi));
}

struct fragp { bf16x8 h, l; };   // hi/lo weight fragment pair

// B-frag pair for C = A @ W^T, W fp32 row-major [Hr][Kr]; lane col n holds
// W[n][kbase..kbase+8) split hi/lo. Zero-pads OOB rows/cols.
__device__ __forceinline__ fragp load_wfrag_hl(const float* W, int Hr, int Kr,
                                               int n, int kbase) {
    u16x8 uh = {0,0,0,0,0,0,0,0}, ul = {0,0,0,0,0,0,0,0};
    if (n < Hr) {
#pragma unroll
        for (int j = 0; j < 8; j++) {
            int k = kbase + j;
            if (k < Kr) {
                float w = W[n * Kr + k];
                u16 hi = f2bf(w);
                uh[j] = hi;
                ul[j] = f2bf(w - bf2f(hi));
            }
        }
    }
    fragp r;
    r.h = __builtin_bit_cast(bf16x8, uh);
    r.l = __builtin_bit_cast(bf16x8, ul);
    return r;
}

// 3-term double-bf16 product accumulate: c += (ah+al) * (bh+bl) - O(2^-18)
__device__ __forceinline__ f32x4 mm3(bf16x8 ah, bf16x8 al, const fragp& b, f32x4 c) {
    c = MFMA16(ah, b.h, c);
    c = MFMA16(ah, b.l, c);
    c = MFMA16(al, b.h, c);
    return c;
}

__global__ __launch_bounds__(512, 2)  // 8 waves, 2/SIMD: 256-reg/wave budget
void rnn_fused(const float* __restrict__ x,
               const float* __restrict__ wih0, const float* __restrict__ whh0,
               const float* __restrict__ bih0, const float* __restrict__ bhh0,
               const float* __restrict__ wih1, const float* __restrict__ whh1,
               const float* __restrict__ bih1, const float* __restrict__ bhh1,
               const float* __restrict__ wih2, const float* __restrict__ whh2,
               const float* __restrict__ bih2, const float* __restrict__ bhh2,
               float* __restrict__ out)
{
    // hi/lo planes, double-buffered by t parity. Row strides 136/104/96 els:
    // 16B-aligned rows for ds_read_b128; 2-way bank alias is free (m136).
    __shared__ __align__(16) u16 h0h[2][32][136], h0l[2][32][136];
    __shared__ __align__(16) u16 h1h[2][32][136], h1l[2][32][136];
    __shared__ __align__(16) u16 h2h[2][32][104], h2l[2][32][104];
    __shared__ __align__(16) u16 xbh[2][32][96],  xbl[2][32][96];   // x_t staging

    const int tid  = threadIdx.x;
    const int wv   = tid >> 6;        // wave 0..7
    const int lane = tid & 63;
    const int ln   = lane & 15;       // A-row / C-col index
    const int q    = lane >> 4;       // quad
    // wave -> n-tile map: {0,1,2}->+{0,1,2}, 3->6, {4,5,6}->{3,4,5}, 7->7.
    // Tiles 6,7 (cols 96..127) are L2-dead; they land on waves 3,7 = SIMD 3,
    // keeping SIMDs 0-2 at 2 active waves during L2.
    const int nt   = ((wv & 3) == 3) ? (6 + (wv >> 2)) : ((wv >> 2) * 3 + (wv & 3));
    const int nw   = nt * 16 + ln;    // owned output column (0..127)
    const int b0   = blockIdx.x * 32;
    const float* xg = x + (long)b0 * 5376;   // this block's 32 batch rows

    // h_{-1} = 0 (parity-0 planes)
    { u16* z = &h0h[0][0][0]; for (int i = tid; i < 32 * 136; i += 512) z[i] = 0; }
    { u16* z = &h0l[0][0][0]; for (int i = tid; i < 32 * 136; i += 512) z[i] = 0; }
    { u16* z = &h1h[0][0][0]; for (int i = tid; i < 32 * 136; i += 512) z[i] = 0; }
    { u16* z = &h1l[0][0][0]; for (int i = tid; i < 32 * 136; i += 512) z[i] = 0; }
    { u16* z = &h2h[0][0][0]; for (int i = tid; i < 32 * 104; i += 512) z[i] = 0; }
    { u16* z = &h2l[0][0][0]; for (int i = tid; i < 32 * 104; i += 512) z[i] = 0; }
    // x pad cols 84..95, both parities, both planes (written once)
    for (int i = tid; i < 32 * 12 * 2; i += 512) {
        int par = i / (32 * 12), rem = i - par * 32 * 12;
        int row = rem / 12, col = 84 + rem - row * 12;
        xbh[par][row][col] = 0; xbl[par][row][col] = 0;
    }
    // stage x_0 into parity 0
    for (int i = tid; i < 32 * 84; i += 512) {
        int row = i / 84, col = i - row * 84;
        float v = xg[(long)row * 5376 + col];
        u16 hi = f2bf(v);
        xbh[0][row][col] = hi;
        xbl[0][row][col] = f2bf(v - bf2f(hi));
    }

    // ---- register-resident hi/lo weight B-frags: 22 fragp = 176 VGPRs ----
    fragp fih0[3], fhh0[4], fih1[4], fhh1[4], fih2[4], fhh2[3];
#pragma unroll
    for (int c = 0; c < 3; c++) {
        fih0[c] = load_wfrag_hl(wih0, 128, 84, nw, c * 32 + q * 8);
        fhh2[c] = load_wfrag_hl(whh2,  84, 84, nw, c * 32 + q * 8);  // nw>=84 -> zeros
    }
#pragma unroll
    for (int c = 0; c < 4; c++) {
        fhh0[c] = load_wfrag_hl(whh0, 128, 128, nw, c * 32 + q * 8);
        fih1[c] = load_wfrag_hl(wih1, 128, 128, nw, c * 32 + q * 8);
        fhh1[c] = load_wfrag_hl(whh1, 128, 128, nw, c * 32 + q * 8);
        fih2[c] = load_wfrag_hl(wih2,  84, 128, nw, c * 32 + q * 8); // nw>=84 -> zeros
    }
    const float bias0w = bih0[nw] + bhh0[nw];                  // nw < 128 always
    const float bias1w = bih1[nw] + bhh1[nw];
    const float bias2w = (nw < 84) ? bih2[nw] + bhh2[nw] : 0.f;

    __syncthreads();

    f32x4 acc0, acc1;        // [m-tile 0/1] for this wave's single n-tile
    float xs[6];             // T14 issue-early staging regs (32*84/512 = 5.25)
    // barrier-shadow prefetch buffers: [c-chunk 0/1][m-tile 0/1], hi/lo.
    // All indices compile-time after unroll (rule #20).
    bf16x8 pfh[2][2], pfl[2][2];
#pragma unroll
    for (int c = 0; c < 2; c++) {
#pragma unroll
        for (int m = 0; m < 2; m++) { pfh[c][m] = zero8(); pfl[c][m] = zero8(); }
    }   // t=0 L0 recurrence operand h_{-1} = 0

    for (int t = 0; t < 64; ++t) {
        const int p = t & 1, pn = p ^ 1;

        // -- T14 issue-early: global loads for x_{t+1}; consumed after bar 1.
        if (t < 63) {
#pragma unroll
            for (int j = 0; j < 6; j++) {
                int i = tid + j * 512;
                if (i < 32 * 84) {
                    int row = i / 84, col = i - row * 84;
                    xs[j] = xg[(long)row * 5376 + (t + 1) * 84 + col];
                }
            }
        }

        // ================= layer 0 : 84 -> 128 =================
        acc0 = splat4(bias0w); acc1 = splat4(bias0w);
        // consume prefetched h0[p] recurrence chunks c=0,1 (pure-reg MFMAs)
        __builtin_amdgcn_s_setprio(1);
#pragma unroll
        for (int c = 0; c < 2; c++) {
            acc0 = mm3(pfh[c][0], pfl[c][0], fhh0[c], acc0);
            acc1 = mm3(pfh[c][1], pfl[c][1], fhh0[c], acc1);
        }
        __builtin_amdgcn_s_setprio(0);
#pragma unroll
        for (int c = 2; c < 4; c++) {            // recurrence, demand chunks
            const int off = c * 32 + q * 8;
            bf16x8 a0h = ld_lds8(&h0h[p][ln][off]),      a0l = ld_lds8(&h0l[p][ln][off]);
            bf16x8 a1h = ld_lds8(&h0h[p][16 + ln][off]), a1l = ld_lds8(&h0l[p][16 + ln][off]);
            acc0 = mm3(a0h, a0l, fhh0[c], acc0);
            acc1 = mm3(a1h, a1l, fhh0[c], acc1);
        }
#pragma unroll
        for (int c = 0; c < 3; c++) {            // x-projection from staged x_t
            const int off = c * 32 + q * 8;
            bf16x8 a0h = ld_lds8(&xbh[p][ln][off]),      a0l = ld_lds8(&xbl[p][ln][off]);
            bf16x8 a1h = ld_lds8(&xbh[p][16 + ln][off]), a1l = ld_lds8(&xbl[p][16 + ln][off]);
            acc0 = mm3(a0h, a0l, fih0[c], acc0);
            acc1 = mm3(a1h, a1l, fih0[c], acc1);
        }
#pragma unroll
        for (int r = 0; r < 4; r++) {            // C/D: row = q*4+r, col = nw
            const int row = q * 4 + r;
            store_hl(&h0h[pn][row     ][nw], &h0l[pn][row     ][nw], tanh_fast(acc0[r]));
            store_hl(&h0h[pn][16 + row][nw], &h0l[pn][16 + row][nw], tanh_fast(acc1[r]));
        }
        // barrier-shadow prefetch: L1 recurrence h1[p] c=0,1 (stable parity;
        // last writer finished before b2(t-1) < b1(t)). Reads overlap the
        // epilogue VALU above; __syncthreads' lgkmcnt(0) drain completes them.
#pragma unroll
        for (int c = 0; c < 2; c++) {
            const int off = c * 32 + q * 8;
            pfh[c][0] = ld_lds8(&h1h[p][ln][off]);      pfl[c][0] = ld_lds8(&h1l[p][ln][off]);
            pfh[c][1] = ld_lds8(&h1h[p][16 + ln][off]); pfl[c][1] = ld_lds8(&h1l[p][16 + ln][off]);
        }
        __syncthreads();   // barrier 1: h0_t ready for L1

        // write-late half of x_{t+1} staging into xbuf[pn]
        // (read by L0 of t+1 after barrier 2 -> safe, same slot as R3/R4)
        if (t < 63) {
#pragma unroll
            for (int j = 0; j < 6; j++) {
                int i = tid + j * 512;
                if (i < 32 * 84) {
                    int row = i / 84, col = i - row * 84;
                    u16 hi = f2bf(xs[j]);
                    xbh[pn][row][col] = hi;
                    xbl[pn][row][col] = f2bf(xs[j] - bf2f(hi));
                }
            }
        }

        // ================= layer 1 : 128 -> 128 =================
        acc0 = splat4(bias1w); acc1 = splat4(bias1w);
        // consume prefetched h1[p] recurrence chunks c=0,1 first
        __builtin_amdgcn_s_setprio(1);
#pragma unroll
        for (int c = 0; c < 2; c++) {
            acc0 = mm3(pfh[c][0], pfl[c][0], fhh1[c], acc0);
            acc1 = mm3(pfh[c][1], pfl[c][1], fhh1[c], acc1);
        }
        __builtin_amdgcn_s_setprio(0);
#pragma unroll
        for (int c = 2; c < 4; c++) {            // recurrence, demand chunks
            const int off = c * 32 + q * 8;
            bf16x8 a0h = ld_lds8(&h1h[p][ln][off]),      a0l = ld_lds8(&h1l[p][ln][off]);
            bf16x8 a1h = ld_lds8(&h1h[p][16 + ln][off]), a1l = ld_lds8(&h1l[p][16 + ln][off]);
            acc0 = mm3(a0h, a0l, fhh1[c], acc0);
            acc1 = mm3(a1h, a1l, fhh1[c], acc1);
        }
#pragma unroll
        for (int c = 0; c < 4; c++) {            // input proj from h0_t
            const int off = c * 32 + q * 8;
            bf16x8 a0h = ld_lds8(&h0h[pn][ln][off]),      a0l = ld_lds8(&h0l[pn][ln][off]);
            bf16x8 a1h = ld_lds8(&h0h[pn][16 + ln][off]), a1l = ld_lds8(&h0l[pn][16 + ln][off]);
            acc0 = mm3(a0h, a0l, fih1[c], acc0);
            acc1 = mm3(a1h, a1l, fih1[c], acc1);
        }
#pragma unroll
        for (int r = 0; r < 4; r++) {
            const int row = q * 4 + r;
            store_hl(&h1h[pn][row     ][nw], &h1l[pn][row     ][nw], tanh_fast(acc0[r]));
            store_hl(&h1h[pn][16 + row][nw], &h1l[pn][16 + row][nw], tanh_fast(acc1[r]));
        }
        // barrier-shadow prefetch: L2 recurrence h2[p] c=0,1 (written by
        // L2(t-1) epilogue, separated from this read by b1(t)).
        if (nt < 6) {
#pragma unroll
            for (int c = 0; c < 2; c++) {
                const int off = c * 32 + q * 8;
                pfh[c][0] = ld_lds8(&h2h[p][ln][off]);      pfl[c][0] = ld_lds8(&h2l[p][ln][off]);
                pfh[c][1] = ld_lds8(&h2h[p][16 + ln][off]); pfl[c][1] = ld_lds8(&h2l[p][16 + ln][off]);
            }
        }
        __syncthreads();   // barrier 2: h1_t (and x_{t+1}) ready

        // ================= layer 2 : 128 -> 84 =================
        // Tiles 6,7 (waves 3,7) are all-padding: skip entirely. Safe: no
        // barrier after L2 (audit as R4).
        if (nt < 6) {
            acc0 = splat4(bias2w); acc1 = splat4(bias2w);
            // consume prefetched h2[p] recurrence chunks c=0,1 first
            __builtin_amdgcn_s_setprio(1);
#pragma unroll
            for (int c = 0; c < 2; c++) {
                acc0 = mm3(pfh[c][0], pfl[c][0], fhh2[c], acc0);
                acc1 = mm3(pfh[c][1], pfl[c][1], fhh2[c], acc1);
            }
            __builtin_amdgcn_s_setprio(0);
            {                                    // recurrence tail chunk c=2
                const int off = 2 * 32 + q * 8;
                bf16x8 a0h = ld_lds8(&h2h[p][ln][off]),      a0l = ld_lds8(&h2l[p][ln][off]);
                bf16x8 a1h = ld_lds8(&h2h[p][16 + ln][off]), a1l = ld_lds8(&h2l[p][16 + ln][off]);
                acc0 = mm3(a0h, a0l, fhh2[2], acc0);
                acc1 = mm3(a1h, a1l, fhh2[2], acc1);
            }
#pragma unroll
            for (int c = 0; c < 4; c++) {        // input proj from h1_t
                const int off = c * 32 + q * 8;
                bf16x8 a0h = ld_lds8(&h1h[pn][ln][off]),      a0l = ld_lds8(&h1l[pn][ln][off]);
                bf16x8 a1h = ld_lds8(&h1h[pn][16 + ln][off]), a1l = ld_lds8(&h1l[pn][16 + ln][off]);
                acc0 = mm3(a0h, a0l, fih2[c], acc0);
                acc1 = mm3(a1h, a1l, fih2[c], acc1);
            }
            // epilogue: pad cols (84..95) compute to exactly 0 (zeroed W+bias)
#pragma unroll
            for (int r = 0; r < 4; r++) {
                const int row = q * 4 + r;
                float v0 = tanh_fast(acc0[r]);
                float v1 = tanh_fast(acc1[r]);
                store_hl(&h2h[pn][row     ][nw], &h2l[pn][row     ][nw], v0);
                store_hl(&h2h[pn][16 + row][nw], &h2l[pn][16 + row][nw], v1);
                if (nw < 84) {
                    out[(long)(b0 + row)      * 5376 + t * 84 + nw] = v0;
                    out[(long)(b0 + 16 + row) * 5376 + t * 84 + nw] = v1;
                }
            }
        }
        // loop-bottom prefetch: next-t L0 recurrence h0[pn] c=0,1.
        // h0[pn] stable since b1(t); racing waves (3,7 already in t+1's L0)
        // write h0[p] = other parity -> safe. Wasted (harmless) at t=63.
#pragma unroll
        for (int c = 0; c < 2; c++) {
            const int off = c * 32 + q * 8;
            pfh[c][0] = ld_lds8(&h0h[pn][ln][off]);      pfl[c][0] = ld_lds8(&h0l[pn][ln][off]);
            pfh[c][1] = ld_lds8(&h0h[pn][16 + ln][off]); pfl[c][1] = ld_lds8(&h0l[pn][16 + ln][off]);
        }
    }
}

extern "C" void kernel_launch(void* const* d_in, const int* in_sizes, int n_in,
                              void* d_out, int out_size, void* d_ws, size_t ws_size,
                              hipStream_t stream) {
    (void)in_sizes; (void)n_in; (void)out_size; (void)d_ws; (void)ws_size;
    const float* x    = (const float*)d_in[0];
    const float* wih0 = (const float*)d_in[1];
    const float* whh0 = (const float*)d_in[2];
    const float* bih0 = (const float*)d_in[3];
    const float* bhh0 = (const float*)d_in[4];
    const float* wih1 = (const float*)d_in[5];
    const float* whh1 = (const float*)d_in[6];
    const float* bih1 = (const float*)d_in[7];
    const float* bhh1 = (const float*)d_in[8];
    const float* wih2 = (const float*)d_in[9];
    const float* whh2 = (const float*)d_in[10];
    const float* bih2 = (const float*)d_in[11];
    const float* bhh2 = (const float*)d_in[12];
    float* out = (float*)d_out;

    rnn_fused<<<dim3(8192 / 32), dim3(512), 0, stream>>>(
        x, wih0, whh0, bih0, bhh0, wih1, whh1, bih1, bhh1,
        wih2, whh2, bih2, bhh2, out);
}

// Round 3
// 586.431 us; speedup vs baseline: 1.4648x; 1.4648x over previous
//
#include <hip/hip_runtime.h>

// ============================================================================
// Fully-fused 3-layer Elman RNN, *** FP32 in/out ***, MFMA 16x16x32 bf16 via
// Ootomo 3-term double-bf16 products (ah*bh + ah*bl + al*bh, err ~2^-18).
//   B=8192, T=64, dims: 84 -> 128 -> 128 -> 84
// R6: warp-specialized layer pipeline ("fat waves without the reg blowup").
//   R4 floors: MFMA ~4.7k cy/step, LDS ~8.5k (8 thin waves each re-read the
//   whole A-panel). R5 (prefetch, +32 regs) spilled to scratch: FETCH 90->232MB.
//   Fix: split LAYERS across 2 wave groups; each wave is fat (2 n-tiles,
//   halves A-panel traffic) but holds only its layers' weights = 176 regs
//   (R4's proven-fitting budget):
//     group A (waves 0-3, 1/SIMD): L0-rec (fhh0) + L2 (fih2,fhh2) = 22 fragp
//     group B (waves 4-7):         L1 (fih1,fhh1) + L0-proj (fih0) = 22 fragp
//   B computes xp(t)=x_t@wih0^T+bias0 one round early -> f32 LDS (swizzled);
//   A inits L0 acc from xp. Pipeline (67 rounds): A: L0(rr-1), L2(rr-3);
//   B: L1(rr-2), XP(rr). ALL buffers: write parity [PN], read [P], every
//   producer->consumer gap exactly 1 round => ONE barrier/round (vs 128),
//   no intra-round hazards. __syncthreads in divergent branches: every wave
//   arrives exactly 67 times (standard producer/consumer; s_barrier counts
//   wave arrivals). setprio(1) wraps MFMA clusters (T5 regime: role-split
//   waves now real). Numerics unchanged (same hi/lo paths; xp kept f32;
//   only fp32 accumulation order changes).
// ============================================================================

typedef __bf16 bf16x8 __attribute__((ext_vector_type(8)));
typedef float  f32x4  __attribute__((ext_vector_type(4)));
typedef unsigned short u16;
typedef unsigned int   u32;
typedef u16 u16x8 __attribute__((ext_vector_type(8)));

#define MFMA16(a, b, c) __builtin_amdgcn_mfma_f32_16x16x32_bf16((a), (b), (c), 0, 0, 0)

__device__ __forceinline__ float bf2f(u16 v) {
    return __builtin_bit_cast(float, (u32)v << 16);
}
__device__ __forceinline__ u16 f2bf(float f) {
    u32 u = __builtin_bit_cast(u32, f);
    u = u + 0x7fffu + ((u >> 16) & 1u);
    return (u16)(u >> 16);
}
__device__ __forceinline__ float tanh_fast(float x) {
    float xc = fminf(fmaxf(x, -12.f), 12.f);
    float e  = __expf(2.f * xc);
    return (e - 1.f) * __builtin_amdgcn_rcpf(e + 1.f);
}
__device__ __forceinline__ f32x4 splat4(float v) {
    f32x4 r; r[0] = v; r[1] = v; r[2] = v; r[3] = v; return r;
}
__device__ __forceinline__ bf16x8 ld_lds8(const u16* p) {
    return __builtin_bit_cast(bf16x8, *(const u16x8*)p);
}
__device__ __forceinline__ void store_hl(u16* ph, u16* pl, float v) {
    u16 hi = f2bf(v);
    *ph = hi;
    *pl = f2bf(v - bf2f(hi));
}

struct fragp { bf16x8 h, l; };

__device__ __forceinline__ fragp load_wfrag_hl(const float* W, int Hr, int Kr,
                                               int n, int kbase) {
    u16x8 uh = {0,0,0,0,0,0,0,0}, ul = {0,0,0,0,0,0,0,0};
    if (n < Hr) {
#pragma unroll
        for (int j = 0; j < 8; j++) {
            int k = kbase + j;
            if (k < Kr) {
                float w = W[n * Kr + k];
                u16 hi = f2bf(w);
                uh[j] = hi;
                ul[j] = f2bf(w - bf2f(hi));
            }
        }
    }
    fragp r;
    r.h = __builtin_bit_cast(bf16x8, uh);
    r.l = __builtin_bit_cast(bf16x8, ul);
    return r;
}

__device__ __forceinline__ f32x4 mm3(bf16x8 ah, bf16x8 al, const fragp& b, f32x4 c) {
    c = MFMA16(ah, b.h, c);
    c = MFMA16(ah, b.l, c);
    c = MFMA16(al, b.h, c);
    return c;
}

__global__ __launch_bounds__(512, 2)  // 8 waves, 2/SIMD (1 A + 1 B per SIMD)
void rnn_fused(const float* __restrict__ x,
               const float* __restrict__ wih0, const float* __restrict__ whh0,
               const float* __restrict__ bih0, const float* __restrict__ bhh0,
               const float* __restrict__ wih1, const float* __restrict__ whh1,
               const float* __restrict__ bih1, const float* __restrict__ bhh1,
               const float* __restrict__ wih2, const float* __restrict__ whh2,
               const float* __restrict__ bih2, const float* __restrict__ bhh2,
               float* __restrict__ out)
{
    // hi/lo planes, double-buffered by ROUND parity. Strides 136/104/96.
    __shared__ __align__(16) u16 h0h[2][32][136], h0l[2][32][136];
    __shared__ __align__(16) u16 h1h[2][32][136], h1l[2][32][136];
    __shared__ __align__(16) u16 h2h[2][32][104], h2l[2][32][104];
    __shared__ __align__(16) u16 xbh[2][32][96],  xbl[2][32][96];
    // xp(t) = x_t@wih0^T + bias0, f32, [parity][col][row], row XOR-swizzled
    // by ((col&7)<<2) at 4-word granularity (write & read apply same XOR).
    __shared__ __align__(16) float xpT[2][128][32];   // 32 KiB; total 150 KiB

    const int tid  = threadIdx.x;
    const int wv   = tid >> 6;        // wave 0..7; SIMD = wv&3
    const int lane = tid & 63;
    const int ln   = lane & 15;       // A-row / C-col fragment index
    const int q    = lane >> 4;       // quad
    const int aw   = wv & 3;          // group-local wave id 0..3
    const bool isA = (wv < 4);        // waves 0-3 = group A, 4-7 = group B
    const int xsw  = (ln & 7) << 2;   // xpT row swizzle (col&7 == ln&7)
    const int b0   = blockIdx.x * 32;
    const float* xg = x + (long)b0 * 5376;

    // n-tile pair {2aw, 2aw+1} -> cols:
    const int col0 = aw * 32 + ln;
    const int col1 = aw * 32 + 16 + ln;

    // ---- prologue: zero the recurrence-init planes (first-READ parities):
    // h0[-1] read at rr=1 (P=1); h1[-1] at rr=2 (P=0); h2[-1] at rr=3 (P=1).
    { u16* z = &h0h[1][0][0]; for (int i = tid; i < 32 * 136; i += 512) z[i] = 0; }
    { u16* z = &h0l[1][0][0]; for (int i = tid; i < 32 * 136; i += 512) z[i] = 0; }
    { u16* z = &h1h[0][0][0]; for (int i = tid; i < 32 * 136; i += 512) z[i] = 0; }
    { u16* z = &h1l[0][0][0]; for (int i = tid; i < 32 * 136; i += 512) z[i] = 0; }
    { u16* z = &h2h[1][0][0]; for (int i = tid; i < 32 * 104; i += 512) z[i] = 0; }
    { u16* z = &h2l[1][0][0]; for (int i = tid; i < 32 * 104; i += 512) z[i] = 0; }
    // x pad cols 84..95, both parities (written once, stay zero)
    for (int i = tid; i < 32 * 12 * 2; i += 512) {
        int par = i / (32 * 12), rem = i - par * 32 * 12;
        int row = rem / 12, col = 84 + rem - row * 12;
        xbh[par][row][col] = 0; xbl[par][row][col] = 0;
    }
    // stage x(0) -> xb[0] (read by XP(0) at rr=0, P=0)
    for (int i = tid; i < 32 * 84; i += 512) {
        int row = i / 84, col = i - row * 84;
        float v = xg[(long)row * 5376 + col];
        u16 hi = f2bf(v);
        xbh[0][row][col] = hi;
        xbl[0][row][col] = f2bf(v - bf2f(hi));
    }

    __syncthreads();   // prologue barrier (uniform, before specialization)

    // =====================================================================
    // Pipeline, 67 rounds. At round rr (P=rr&1, PN=P^1), reads from [P],
    // writes to [PN]; ONE barrier flips parity:
    //   A: L0(t=rr-1)  [xp[P], h0[P]rec -> h0[PN]]          rr in [1,64]
    //   A: L2(t=rr-3)  [h1[P]proj, h2[P]rec -> h2[PN], out] rr in [3,66]
    //   B: L1(t=rr-2)  [h0[P]proj, h1[P]rec -> h1[PN]]      rr in [2,65]
    //   B: XP(t=rr)    [xb[P] -> xpT[PN]]                   rr in [0,63]
    //   all: stage x(rr+1) -> xb[PN]                        rr in [0,62]
    // Every producer->consumer gap is exactly 1 round => parity dbuf sound.
    // =====================================================================
    if (isA) {
        // ---- group A weights: 22 fragp = 176 regs ----
        fragp fhh0[2][4], fih2[2][4], fhh2[2][3];
#pragma unroll
        for (int c = 0; c < 4; c++) {
            fhh0[0][c] = load_wfrag_hl(whh0, 128, 128, col0, c * 32 + q * 8);
            fhh0[1][c] = load_wfrag_hl(whh0, 128, 128, col1, c * 32 + q * 8);
            fih2[0][c] = load_wfrag_hl(wih2,  84, 128, col0, c * 32 + q * 8);
            fih2[1][c] = load_wfrag_hl(wih2,  84, 128, col1, c * 32 + q * 8);
        }
#pragma unroll
        for (int c = 0; c < 3; c++) {
            fhh2[0][c] = load_wfrag_hl(whh2, 84, 84, col0, c * 32 + q * 8);
            fhh2[1][c] = load_wfrag_hl(whh2, 84, 84, col1, c * 32 + q * 8);
        }
        const float bias2c[2] = { (col0 < 84) ? bih2[col0] + bhh2[col0] : 0.f,
                                  (col1 < 84) ? bih2[col1] + bhh2[col1] : 0.f };

        f32x4 acc[2][2];   // [n-tile][m-tile]
        float xs[6];

        for (int rr = 0; rr < 67; ++rr) {
            const int P = rr & 1, PN = P ^ 1;

            if (rr <= 62) {                        // issue-early x(rr+1) loads
#pragma unroll
                for (int j = 0; j < 6; j++) {
                    int i = tid + j * 512;
                    if (i < 2688) {
                        int row = i / 84, cc = i - row * 84;
                        xs[j] = xg[(long)row * 5376 + (rr + 1) * 84 + cc];
                    }
                }
            }

            // ---------- L0(t=rr-1): xp-init + 4 rec chunks ----------
            if (rr >= 1 && rr <= 64) {
#pragma unroll
                for (int n2 = 0; n2 < 2; n2++) {
                    const int colx = aw * 32 + n2 * 16 + ln;
                    acc[n2][0] = *(const f32x4*)&xpT[P][colx][(4 * q) ^ xsw];
                    acc[n2][1] = *(const f32x4*)&xpT[P][colx][(16 + 4 * q) ^ xsw];
                }
                __builtin_amdgcn_s_setprio(1);
#pragma unroll
                for (int c = 0; c < 4; c++) {
                    const int off = c * 32 + q * 8;
                    bf16x8 a0h = ld_lds8(&h0h[P][ln][off]),      a0l = ld_lds8(&h0l[P][ln][off]);
                    bf16x8 a1h = ld_lds8(&h0h[P][16 + ln][off]), a1l = ld_lds8(&h0l[P][16 + ln][off]);
                    acc[0][0] = mm3(a0h, a0l, fhh0[0][c], acc[0][0]);
                    acc[1][0] = mm3(a0h, a0l, fhh0[1][c], acc[1][0]);
                    acc[0][1] = mm3(a1h, a1l, fhh0[0][c], acc[0][1]);
                    acc[1][1] = mm3(a1h, a1l, fhh0[1][c], acc[1][1]);
                }
                __builtin_amdgcn_s_setprio(0);
#pragma unroll
                for (int r = 0; r < 4; r++) {
                    const int row = q * 4 + r;
                    store_hl(&h0h[PN][row     ][col0], &h0l[PN][row     ][col0], tanh_fast(acc[0][0][r]));
                    store_hl(&h0h[PN][row     ][col1], &h0l[PN][row     ][col1], tanh_fast(acc[1][0][r]));
                    store_hl(&h0h[PN][16 + row][col0], &h0l[PN][16 + row][col0], tanh_fast(acc[0][1][r]));
                    store_hl(&h0h[PN][16 + row][col1], &h0l[PN][16 + row][col1], tanh_fast(acc[1][1][r]));
                }
            }

            // ---------- L2(t=rr-3): proj(h1) + rec(h2) ----------
            // wave aw=3 owns tiles {6,7} = cols 96..127, all dead -> skip.
            if (aw != 3 && rr >= 3) {
                const int t2 = rr - 3;
                acc[0][0] = splat4(bias2c[0]); acc[0][1] = splat4(bias2c[0]);
                acc[1][0] = splat4(bias2c[1]); acc[1][1] = splat4(bias2c[1]);
                __builtin_amdgcn_s_setprio(1);
#pragma unroll
                for (int c = 0; c < 4; c++) {
                    const int off = c * 32 + q * 8;
                    bf16x8 a0h = ld_lds8(&h1h[P][ln][off]),      a0l = ld_lds8(&h1l[P][ln][off]);
                    bf16x8 a1h = ld_lds8(&h1h[P][16 + ln][off]), a1l = ld_lds8(&h1l[P][16 + ln][off]);
                    acc[0][0] = mm3(a0h, a0l, fih2[0][c], acc[0][0]);
                    acc[1][0] = mm3(a0h, a0l, fih2[1][c], acc[1][0]);
                    acc[0][1] = mm3(a1h, a1l, fih2[0][c], acc[0][1]);
                    acc[1][1] = mm3(a1h, a1l, fih2[1][c], acc[1][1]);
                }
#pragma unroll
                for (int c = 0; c < 3; c++) {
                    const int off = c * 32 + q * 8;
                    bf16x8 a0h = ld_lds8(&h2h[P][ln][off]),      a0l = ld_lds8(&h2l[P][ln][off]);
                    bf16x8 a1h = ld_lds8(&h2h[P][16 + ln][off]), a1l = ld_lds8(&h2l[P][16 + ln][off]);
                    acc[0][0] = mm3(a0h, a0l, fhh2[0][c], acc[0][0]);
                    acc[1][0] = mm3(a0h, a0l, fhh2[1][c], acc[1][0]);
                    acc[0][1] = mm3(a1h, a1l, fhh2[0][c], acc[0][1]);
                    acc[1][1] = mm3(a1h, a1l, fhh2[1][c], acc[1][1]);
                }
                __builtin_amdgcn_s_setprio(0);
#pragma unroll
                for (int r = 0; r < 4; r++) {
                    const int row = q * 4 + r;
                    float v00 = tanh_fast(acc[0][0][r]);   // col0, row
                    float v10 = tanh_fast(acc[0][1][r]);   // col0, 16+row
                    float v01 = tanh_fast(acc[1][0][r]);   // col1, row
                    float v11 = tanh_fast(acc[1][1][r]);   // col1, 16+row
                    store_hl(&h2h[PN][row     ][col0], &h2l[PN][row     ][col0], v00);
                    store_hl(&h2h[PN][16 + row][col0], &h2l[PN][16 + row][col0], v10);
                    store_hl(&h2h[PN][row     ][col1], &h2l[PN][row     ][col1], v01);  // col1<=95<104
                    store_hl(&h2h[PN][16 + row][col1], &h2l[PN][16 + row][col1], v11);
                    float* o0 = out + (long)(b0 + row)      * 5376 + t2 * 84;
                    float* o1 = out + (long)(b0 + 16 + row) * 5376 + t2 * 84;
                    if (col0 < 84) { o0[col0] = v00; o1[col0] = v10; }
                    if (col1 < 84) { o0[col1] = v01; o1[col1] = v11; }
                }
            }

            if (rr <= 62) {                        // write-late x staging
#pragma unroll
                for (int j = 0; j < 6; j++) {
                    int i = tid + j * 512;
                    if (i < 2688) {
                        int row = i / 84, cc = i - row * 84;
                        u16 hi = f2bf(xs[j]);
                        xbh[PN][row][cc] = hi;
                        xbl[PN][row][cc] = f2bf(xs[j] - bf2f(hi));
                    }
                }
            }
            __syncthreads();   // the round barrier (1 of 1)
        }
    } else {
        // ---- group B weights: 22 fragp = 176 regs ----
        fragp fih0[2][3], fih1[2][4], fhh1[2][4];
#pragma unroll
        for (int c = 0; c < 3; c++) {
            fih0[0][c] = load_wfrag_hl(wih0, 128, 84, col0, c * 32 + q * 8);
            fih0[1][c] = load_wfrag_hl(wih0, 128, 84, col1, c * 32 + q * 8);
        }
#pragma unroll
        for (int c = 0; c < 4; c++) {
            fih1[0][c] = load_wfrag_hl(wih1, 128, 128, col0, c * 32 + q * 8);
            fih1[1][c] = load_wfrag_hl(wih1, 128, 128, col1, c * 32 + q * 8);
            fhh1[0][c] = load_wfrag_hl(whh1, 128, 128, col0, c * 32 + q * 8);
            fhh1[1][c] = load_wfrag_hl(whh1, 128, 128, col1, c * 32 + q * 8);
        }
        const float bias0c[2] = { bih0[col0] + bhh0[col0], bih0[col1] + bhh0[col1] };
        const float bias1c[2] = { bih1[col0] + bhh1[col0], bih1[col1] + bhh1[col1] };

        f32x4 acc[2][2];
        float xs[6];

        for (int rr = 0; rr < 67; ++rr) {
            const int P = rr & 1, PN = P ^ 1;

            if (rr <= 62) {                        // issue-early x(rr+1) loads
#pragma unroll
                for (int j = 0; j < 6; j++) {
                    int i = tid + j * 512;
                    if (i < 2688) {
                        int row = i / 84, cc = i - row * 84;
                        xs[j] = xg[(long)row * 5376 + (rr + 1) * 84 + cc];
                    }
                }
            }

            // ---------- L1(t=rr-2): proj(h0) + rec(h1) ----------
            if (rr >= 2 && rr <= 65) {
                acc[0][0] = splat4(bias1c[0]); acc[0][1] = splat4(bias1c[0]);
                acc[1][0] = splat4(bias1c[1]); acc[1][1] = splat4(bias1c[1]);
                __builtin_amdgcn_s_setprio(1);
#pragma unroll
                for (int c = 0; c < 4; c++) {
                    const int off = c * 32 + q * 8;
                    bf16x8 a0h = ld_lds8(&h0h[P][ln][off]),      a0l = ld_lds8(&h0l[P][ln][off]);
                    bf16x8 a1h = ld_lds8(&h0h[P][16 + ln][off]), a1l = ld_lds8(&h0l[P][16 + ln][off]);
                    acc[0][0] = mm3(a0h, a0l, fih1[0][c], acc[0][0]);
                    acc[1][0] = mm3(a0h, a0l, fih1[1][c], acc[1][0]);
                    acc[0][1] = mm3(a1h, a1l, fih1[0][c], acc[0][1]);
                    acc[1][1] = mm3(a1h, a1l, fih1[1][c], acc[1][1]);
                }
#pragma unroll
                for (int c = 0; c < 4; c++) {
                    const int off = c * 32 + q * 8;
                    bf16x8 a0h = ld_lds8(&h1h[P][ln][off]),      a0l = ld_lds8(&h1l[P][ln][off]);
                    bf16x8 a1h = ld_lds8(&h1h[P][16 + ln][off]), a1l = ld_lds8(&h1l[P][16 + ln][off]);
                    acc[0][0] = mm3(a0h, a0l, fhh1[0][c], acc[0][0]);
                    acc[1][0] = mm3(a0h, a0l, fhh1[1][c], acc[1][0]);
                    acc[0][1] = mm3(a1h, a1l, fhh1[0][c], acc[0][1]);
                    acc[1][1] = mm3(a1h, a1l, fhh1[1][c], acc[1][1]);
                }
                __builtin_amdgcn_s_setprio(0);
#pragma unroll
                for (int r = 0; r < 4; r++) {
                    const int row = q * 4 + r;
                    store_hl(&h1h[PN][row     ][col0], &h1l[PN][row     ][col0], tanh_fast(acc[0][0][r]));
                    store_hl(&h1h[PN][row     ][col1], &h1l[PN][row     ][col1], tanh_fast(acc[1][0][r]));
                    store_hl(&h1h[PN][16 + row][col0], &h1l[PN][16 + row][col0], tanh_fast(acc[0][1][r]));
                    store_hl(&h1h[PN][16 + row][col1], &h1l[PN][16 + row][col1], tanh_fast(acc[1][1][r]));
                }
            }

            // ---------- XP(t=rr): x_t @ wih0^T + bias0 -> xpT[PN] (f32) ----
            if (rr <= 63) {
                acc[0][0] = splat4(bias0c[0]); acc[0][1] = splat4(bias0c[0]);
                acc[1][0] = splat4(bias0c[1]); acc[1][1] = splat4(bias0c[1]);
                __builtin_amdgcn_s_setprio(1);
#pragma unroll
                for (int c = 0; c < 3; c++) {
                    const int off = c * 32 + q * 8;
                    bf16x8 a0h = ld_lds8(&xbh[P][ln][off]),      a0l = ld_lds8(&xbl[P][ln][off]);
                    bf16x8 a1h = ld_lds8(&xbh[P][16 + ln][off]), a1l = ld_lds8(&xbl[P][16 + ln][off]);
                    acc[0][0] = mm3(a0h, a0l, fih0[0][c], acc[0][0]);
                    acc[1][0] = mm3(a0h, a0l, fih0[1][c], acc[1][0]);
                    acc[0][1] = mm3(a1h, a1l, fih0[0][c], acc[0][1]);
                    acc[1][1] = mm3(a1h, a1l, fih0[1][c], acc[1][1]);
                }
                __builtin_amdgcn_s_setprio(0);
#pragma unroll
                for (int n2 = 0; n2 < 2; n2++) {
                    const int colx = aw * 32 + n2 * 16 + ln;
                    *(f32x4*)&xpT[PN][colx][(4 * q) ^ xsw]      = acc[n2][0];
                    *(f32x4*)&xpT[PN][colx][(16 + 4 * q) ^ xsw] = acc[n2][1];
                }
            }

            if (rr <= 62) {                        // write-late x staging
#pragma unroll
                for (int j = 0; j < 6; j++) {
                    int i = tid + j * 512;
                    if (i < 2688) {
                        int row = i / 84, cc = i - row * 84;
                        u16 hi = f2bf(xs[j]);
                        xbh[PN][row][cc] = hi;
                        xbl[PN][row][cc] = f2bf(xs[j] - bf2f(hi));
                    }
                }
            }
            __syncthreads();   // the round barrier (1 of 1)
        }
    }
}

extern "C" void kernel_launch(void* const* d_in, const int* in_sizes, int n_in,
                              void* d_out, int out_size, void* d_ws, size_t ws_size,
                              hipStream_t stream) {
    (void)in_sizes; (void)n_in; (void)out_size; (void)d_ws; (void)ws_size;
    const float* x    = (const float*)d_in[0];
    const float* wih0 = (const float*)d_in[1];
    const float* whh0 = (const float*)d_in[2];
    const float* bih0 = (const float*)d_in[3];
    const float* bhh0 = (const float*)d_in[4];
    const float* wih1 = (const float*)d_in[5];
    const float* whh1 = (const float*)d_in[6];
    const float* bih1 = (const float*)d_in[7];
    const float* bhh1 = (const float*)d_in[8];
    const float* wih2 = (const float*)d_in[9];
    const float* whh2 = (const float*)d_in[10];
    const float* bih2 = (const float*)d_in[11];
    const float* bhh2 = (const float*)d_in[12];
    float* out = (float*)d_out;

    rnn_fused<<<dim3(8192 / 32), dim3(512), 0, stream>>>(
        x, wih0, whh0, bih0, bhh0, wih1, whh1, bih1, bhh1,
        wih2, whh2, bih2, bhh2, out);
}

// Round 4
// 558.541 us; speedup vs baseline: 1.5379x; 1.0499x over previous
//
#include <hip/hip_runtime.h>

// ============================================================================
// Fully-fused 3-layer Elman RNN, *** FP32 in/out ***, MFMA via Ootomo 3-term
// double-bf16 products (wh*ah + wl*ah + wh*al, err ~2^-18).
//   B=8192, T=64, dims: 84 -> 128 -> 128 -> 84
// R7 (on R6's warp-specialized pipeline, 424us rocprof): three co-equal cost
// poles (MFMA issue 5.1k SIMD-cy, VALU 5k, LDS ~7k incl. 450 scattered b16
// writes + 1.2k conflict cy from stride-136 rows). One structural change:
//   1) OPERAND-SWAPPED MFMA (weights=A, acts=B): A/B frags share the same
//      lane->(idx,k) map on gfx950, so reads/weight-loads are unchanged, but
//      D transposes: lane = batch row m, regs = 4-consecutive output features
//      -> epilogue writes become packed ds_write_b64 (8/wave vs 32 b16) and
//      L2 global store becomes dwordx4.
//   2) 16x16x32 -> 32x32x16: wave's full 32x32 tile per chunk; MFMA instr
//      count halves, pipe time -17% (8.07 vs 4*4.85 CU-cy per 32x32 chunk).
//   3) h-planes stride 136->128 u16 + XOR swizzle (col ^ ((row&7)<<3)):
//      64-word rows => bank = swizzled col only => b128 reads provably
//      minimal (8 acc/bank). Kills the 4-way stride-136 conflicts.
//   4) xpF[m][n] f32 + same swizzle: XP-write and L0-init both contiguous
//      b128. Biases via small LDS table (broadcast) to keep regs at 176+eps.
// Pipeline/parity/barriers/staging IDENTICAL to R6 (audit carries over):
//   round rr (P=rr&1): A: L0(rr-1), L2(rr-3); B: L1(rr-2), XP(rr);
//   1 barrier/round, every producer->consumer gap exactly 1 round.
// Numerics: same hi/lo paths; only fp32 summation grouping changes (K=16
// chunks vs K=32) -> few-ulp absmax wiggle, far under threshold.
// ============================================================================

typedef __bf16 bf16x8 __attribute__((ext_vector_type(8)));
typedef float  f32x4  __attribute__((ext_vector_type(4)));
typedef float  f32x16 __attribute__((ext_vector_type(16)));
typedef unsigned short u16;
typedef unsigned int   u32;
typedef u16 u16x8 __attribute__((ext_vector_type(8)));
typedef u16 u16x4 __attribute__((ext_vector_type(4)));

#define MFMA32(a, b, c) __builtin_amdgcn_mfma_f32_32x32x16_bf16((a), (b), (c), 0, 0, 0)

__device__ __forceinline__ float bf2f(u16 v) {
    return __builtin_bit_cast(float, (u32)v << 16);
}
__device__ __forceinline__ u16 f2bf(float f) {   // RNE, finite inputs
    u32 u = __builtin_bit_cast(u32, f);
    u = u + 0x7fffu + ((u >> 16) & 1u);
    return (u16)(u >> 16);
}
__device__ __forceinline__ float tanh_fast(float x) {
    float xc = fminf(fmaxf(x, -12.f), 12.f);
    float e  = __expf(2.f * xc);
    return (e - 1.f) * __builtin_amdgcn_rcpf(e + 1.f);
}
__device__ __forceinline__ bf16x8 ld_lds8(const u16* p) {
    return __builtin_bit_cast(bf16x8, *(const u16x8*)p);
}
// activation-plane index (u16 units): row stride 128, XOR-swizzled col.
// Reads are b128 at off multiple of 8 (swizzle bits 3..5 keep 8-alignment);
// writes are b64 at col multiple of 4 (stay inside the 16B swizzle cell).
__device__ __forceinline__ int aswz(int row, int off) {
    return row * 128 + (off ^ ((row & 7) << 3));
}
// xpF index (f32 units): row stride 128, 16B-granular XOR swizzle.
__device__ __forceinline__ int xswz(int m, int n) {
    return m * 128 + (n ^ ((m & 7) << 2));
}
// pack 4 floats -> hi/lo bf16 quads, one ds_write_b64 per plane
__device__ __forceinline__ void store4_hl(u16* ph, u16* pl, f32x4 v) {
    u16x4 hi, lo;
#pragma unroll
    for (int j = 0; j < 4; j++) {
        u16 h = f2bf(v[j]);
        hi[j] = h;
        lo[j] = f2bf(v[j] - bf2f(h));
    }
    *(u16x4*)ph = hi;
    *(u16x4*)pl = lo;
}

struct fragp { bf16x8 h, l; };

// Weight A-frag pair, W fp32 row-major [Hr][Kr]; lane holds W[n][kbase..+8)
// split hi/lo. Zero-pads OOB rows/cols. (32x32x16 A-map: row=lane&31,
// k=(lane>>5)*8+j  — caller passes n=nb+(lane&31), kbase=c*16+(lane>>5)*8.)
__device__ __forceinline__ fragp load_wfrag_hl(const float* W, int Hr, int Kr,
                                               int n, int kbase) {
    u16x8 uh = {0,0,0,0,0,0,0,0}, ul = {0,0,0,0,0,0,0,0};
    if (n < Hr) {
#pragma unroll
        for (int j = 0; j < 8; j++) {
            int k = kbase + j;
            if (k < Kr) {
                float w = W[n * Kr + k];
                u16 hi = f2bf(w);
                uh[j] = hi;
                ul[j] = f2bf(w - bf2f(hi));
            }
        }
    }
    fragp r;
    r.h = __builtin_bit_cast(bf16x8, uh);
    r.l = __builtin_bit_cast(bf16x8, ul);
    return r;
}

// 3-term double-bf16 accumulate, swapped operands: D += (Wh+Wl)(Ah+Al)
__device__ __forceinline__ f32x16 mm3t(const fragp& w, bf16x8 ah, bf16x8 al, f32x16 c) {
    c = MFMA32(w.h, ah, c);
    c = MFMA32(w.l, ah, c);
    c = MFMA32(w.h, al, c);
    return c;
}

__global__ __launch_bounds__(512, 2)  // 8 waves, 2/SIMD (1 A + 1 B per SIMD)
void rnn_fused(const float* __restrict__ x,
               const float* __restrict__ wih0, const float* __restrict__ whh0,
               const float* __restrict__ bih0, const float* __restrict__ bhh0,
               const float* __restrict__ wih1, const float* __restrict__ whh1,
               const float* __restrict__ bih1, const float* __restrict__ bhh1,
               const float* __restrict__ wih2, const float* __restrict__ whh2,
               const float* __restrict__ bih2, const float* __restrict__ bhh2,
               float* __restrict__ out)
{
    // activation hi/lo planes, [parity][32 rows x 128 cols swizzled] u16
    __shared__ __align__(16) u16 h0h[2][4096], h0l[2][4096];
    __shared__ __align__(16) u16 h1h[2][4096], h1l[2][4096];
    __shared__ __align__(16) u16 h2h[2][4096], h2l[2][4096];
    __shared__ __align__(16) u16 xbh[2][32][96], xbl[2][32][96];   // x_t staging
    __shared__ __align__(16) float xpF[2][4096];   // xp(t), [m][n] swizzled f32
    __shared__ float biasF[3][128];                // combined biases per layer

    const int tid  = threadIdx.x;
    const int wv   = tid >> 6;        // wave 0..7; SIMD = wv&3
    const int lane = tid & 63;
    const int mrow = lane & 31;       // batch row (D col after swap)
    const int q2   = lane >> 5;       // k-half
    const int kq   = q2 * 8;
    const int q4   = q2 * 4;
    const int aw   = wv & 3;          // group-local wave id 0..3
    const bool isA = (wv < 4);
    const int nb   = aw * 32;         // owned output-feature block
    const int b0   = blockIdx.x * 32;
    const float* xg = x + (long)b0 * 5376;

    // ---- prologue: zero first-READ parities (h0[-1]@rr=1 P=1; h1[-1]@rr=2
    // P=0; h2[-1]@rr=3 P=1); zeroing is swizzle-agnostic (permutation).
    { u16* z = &h0h[1][0]; for (int i = tid; i < 4096; i += 512) z[i] = 0; }
    { u16* z = &h0l[1][0]; for (int i = tid; i < 4096; i += 512) z[i] = 0; }
    { u16* z = &h1h[0][0]; for (int i = tid; i < 4096; i += 512) z[i] = 0; }
    { u16* z = &h1l[0][0]; for (int i = tid; i < 4096; i += 512) z[i] = 0; }
    { u16* z = &h2h[1][0]; for (int i = tid; i < 4096; i += 512) z[i] = 0; }
    { u16* z = &h2l[1][0]; for (int i = tid; i < 4096; i += 512) z[i] = 0; }
    // x pad cols 84..95, both parities (written once, stay zero)
    for (int i = tid; i < 32 * 12 * 2; i += 512) {
        int par = i / (32 * 12), rem = i - par * 32 * 12;
        int row = rem / 12, col = 84 + rem - row * 12;
        xbh[par][row][col] = 0; xbl[par][row][col] = 0;
    }
    // stage x(0) -> xb[0]
    for (int i = tid; i < 32 * 84; i += 512) {
        int row = i / 84, col = i - row * 84;
        float v = xg[(long)row * 5376 + col];
        u16 hi = f2bf(v);
        xbh[0][row][col] = hi;
        xbl[0][row][col] = f2bf(v - bf2f(hi));
    }
    // combined biases (pad cols -> 0)
    for (int i = tid; i < 384; i += 512) {
        int l = i >> 7, n = i & 127;
        float v = 0.f;
        if (l == 0)      v = bih0[n] + bhh0[n];
        else if (l == 1) v = bih1[n] + bhh1[n];
        else if (n < 84) v = bih2[n] + bhh2[n];
        biasF[l][n] = v;
    }

    __syncthreads();   // prologue barrier

    if (isA) {
        // ---- group A weights: 8+8+6 = 22 fragp = 176 regs ----
        fragp fhh0[8], fih2[8], fhh2[6];
#pragma unroll
        for (int c = 0; c < 8; c++) {
            fhh0[c] = load_wfrag_hl(whh0, 128, 128, nb + mrow, c * 16 + kq);
            fih2[c] = load_wfrag_hl(wih2,  84, 128, nb + mrow, c * 16 + kq);
        }
#pragma unroll
        for (int c = 0; c < 6; c++)
            fhh2[c] = load_wfrag_hl(whh2, 84, 84, nb + mrow, c * 16 + kq);

        float xs[6];
        for (int rr = 0; rr < 67; ++rr) {
            const int P = rr & 1, PN = P ^ 1;

            if (rr <= 62) {                        // issue-early x(rr+1)
#pragma unroll
                for (int j = 0; j < 6; j++) {
                    int i = tid + j * 512;
                    if (i < 2688) {
                        int row = i / 84, cc = i - row * 84;
                        xs[j] = xg[(long)row * 5376 + (rr + 1) * 84 + cc];
                    }
                }
            }

            // ---------- L0(t=rr-1): init from xpF, 8 rec chunks ----------
            if (rr >= 1 && rr <= 64) {
                f32x16 acc;
#pragma unroll
                for (int g = 0; g < 4; g++) {
                    f32x4 v = *(const f32x4*)&xpF[P][xswz(mrow, nb + g * 8 + q4)];
                    acc[4*g+0] = v[0]; acc[4*g+1] = v[1];
                    acc[4*g+2] = v[2]; acc[4*g+3] = v[3];
                }
                __builtin_amdgcn_s_setprio(1);
#pragma unroll
                for (int c = 0; c < 8; c++) {
                    const int idx = aswz(mrow, c * 16 + kq);
                    acc = mm3t(fhh0[c], ld_lds8(&h0h[P][idx]), ld_lds8(&h0l[P][idx]), acc);
                }
                __builtin_amdgcn_s_setprio(0);
#pragma unroll
                for (int g = 0; g < 4; g++) {
                    const int col = nb + g * 8 + q4;
                    f32x4 v;
                    v[0] = tanh_fast(acc[4*g+0]); v[1] = tanh_fast(acc[4*g+1]);
                    v[2] = tanh_fast(acc[4*g+2]); v[3] = tanh_fast(acc[4*g+3]);
                    const int idx = mrow * 128 + (col ^ ((mrow & 7) << 3));
                    store4_hl(&h0h[PN][idx], &h0l[PN][idx], v);
                }
            }

            // ---------- L2(t=rr-3): proj(h1) + rec(h2) ----------
            if (aw != 3 && rr >= 3) {
                const int t2 = rr - 3;
                f32x16 acc;
#pragma unroll
                for (int g = 0; g < 4; g++) {
                    f32x4 v = *(const f32x4*)&biasF[2][nb + g * 8 + q4];
                    acc[4*g+0] = v[0]; acc[4*g+1] = v[1];
                    acc[4*g+2] = v[2]; acc[4*g+3] = v[3];
                }
                __builtin_amdgcn_s_setprio(1);
#pragma unroll
                for (int c = 0; c < 8; c++) {
                    const int idx = aswz(mrow, c * 16 + kq);
                    acc = mm3t(fih2[c], ld_lds8(&h1h[P][idx]), ld_lds8(&h1l[P][idx]), acc);
                }
#pragma unroll
                for (int c = 0; c < 6; c++) {
                    const int idx = aswz(mrow, c * 16 + kq);
                    acc = mm3t(fhh2[c], ld_lds8(&h2h[P][idx]), ld_lds8(&h2l[P][idx]), acc);
                }
                __builtin_amdgcn_s_setprio(0);
#pragma unroll
                for (int g = 0; g < 4; g++) {
                    const int col = nb + g * 8 + q4;
                    f32x4 v;
                    v[0] = tanh_fast(acc[4*g+0]); v[1] = tanh_fast(acc[4*g+1]);
                    v[2] = tanh_fast(acc[4*g+2]); v[3] = tanh_fast(acc[4*g+3]);
                    const int idx = mrow * 128 + (col ^ ((mrow & 7) << 3));
                    store4_hl(&h2h[PN][idx], &h2l[PN][idx], v);
                    if (col < 84)   // 84%4==0 -> all-or-nothing per quad
                        *(f32x4*)(out + (long)(b0 + mrow) * 5376 + t2 * 84 + col) = v;
                }
            }

            if (rr <= 62) {                        // write-late x staging
#pragma unroll
                for (int j = 0; j < 6; j++) {
                    int i = tid + j * 512;
                    if (i < 2688) {
                        int row = i / 84, cc = i - row * 84;
                        u16 hi = f2bf(xs[j]);
                        xbh[PN][row][cc] = hi;
                        xbl[PN][row][cc] = f2bf(xs[j] - bf2f(hi));
                    }
                }
            }
            __syncthreads();   // the round barrier
        }
    } else {
        // ---- group B weights: 6+8+8 = 22 fragp = 176 regs ----
        fragp fih0[6], fih1[8], fhh1[8];
#pragma unroll
        for (int c = 0; c < 6; c++)
            fih0[c] = load_wfrag_hl(wih0, 128, 84, nb + mrow, c * 16 + kq);
#pragma unroll
        for (int c = 0; c < 8; c++) {
            fih1[c] = load_wfrag_hl(wih1, 128, 128, nb + mrow, c * 16 + kq);
            fhh1[c] = load_wfrag_hl(whh1, 128, 128, nb + mrow, c * 16 + kq);
        }

        float xs[6];
        for (int rr = 0; rr < 67; ++rr) {
            const int P = rr & 1, PN = P ^ 1;

            if (rr <= 62) {                        // issue-early x(rr+1)
#pragma unroll
                for (int j = 0; j < 6; j++) {
                    int i = tid + j * 512;
                    if (i < 2688) {
                        int row = i / 84, cc = i - row * 84;
                        xs[j] = xg[(long)row * 5376 + (rr + 1) * 84 + cc];
                    }
                }
            }

            // ---------- L1(t=rr-2): proj(h0) + rec(h1) ----------
            if (rr >= 2 && rr <= 65) {
                f32x16 acc;
#pragma unroll
                for (int g = 0; g < 4; g++) {
                    f32x4 v = *(const f32x4*)&biasF[1][nb + g * 8 + q4];
                    acc[4*g+0] = v[0]; acc[4*g+1] = v[1];
                    acc[4*g+2] = v[2]; acc[4*g+3] = v[3];
                }
                __builtin_amdgcn_s_setprio(1);
#pragma unroll
                for (int c = 0; c < 8; c++) {
                    const int idx = aswz(mrow, c * 16 + kq);
                    acc = mm3t(fih1[c], ld_lds8(&h0h[P][idx]), ld_lds8(&h0l[P][idx]), acc);
                }
#pragma unroll
                for (int c = 0; c < 8; c++) {
                    const int idx = aswz(mrow, c * 16 + kq);
                    acc = mm3t(fhh1[c], ld_lds8(&h1h[P][idx]), ld_lds8(&h1l[P][idx]), acc);
                }
                __builtin_amdgcn_s_setprio(0);
#pragma unroll
                for (int g = 0; g < 4; g++) {
                    const int col = nb + g * 8 + q4;
                    f32x4 v;
                    v[0] = tanh_fast(acc[4*g+0]); v[1] = tanh_fast(acc[4*g+1]);
                    v[2] = tanh_fast(acc[4*g+2]); v[3] = tanh_fast(acc[4*g+3]);
                    const int idx = mrow * 128 + (col ^ ((mrow & 7) << 3));
                    store4_hl(&h1h[PN][idx], &h1l[PN][idx], v);
                }
            }

            // ---------- XP(t=rr): x_t @ wih0^T + bias0 -> xpF[PN] ----------
            if (rr <= 63) {
                f32x16 acc;
#pragma unroll
                for (int g = 0; g < 4; g++) {
                    f32x4 v = *(const f32x4*)&biasF[0][nb + g * 8 + q4];
                    acc[4*g+0] = v[0]; acc[4*g+1] = v[1];
                    acc[4*g+2] = v[2]; acc[4*g+3] = v[3];
                }
                __builtin_amdgcn_s_setprio(1);
#pragma unroll
                for (int c = 0; c < 6; c++) {
                    const int off = c * 16 + kq;   // xb: linear 96-stride rows
                    bf16x8 ah = ld_lds8(&xbh[P][mrow][off]);
                    bf16x8 al = ld_lds8(&xbl[P][mrow][off]);
                    acc = mm3t(fih0[c], ah, al, acc);
                }
                __builtin_amdgcn_s_setprio(0);
#pragma unroll
                for (int g = 0; g < 4; g++) {
                    const int n = nb + g * 8 + q4;
                    f32x4 v;
                    v[0] = acc[4*g+0]; v[1] = acc[4*g+1];
                    v[2] = acc[4*g+2]; v[3] = acc[4*g+3];
                    *(f32x4*)&xpF[PN][xswz(mrow, n)] = v;
                }
            }

            if (rr <= 62) {                        // write-late x staging
#pragma unroll
                for (int j = 0; j < 6; j++) {
                    int i = tid + j * 512;
                    if (i < 2688) {
                        int row = i / 84, cc = i - row * 84;
                        u16 hi = f2bf(xs[j]);
                        xbh[PN][row][cc] = hi;
                        xbl[PN][row][cc] = f2bf(xs[j] - bf2f(hi));
                    }
                }
            }
            __syncthreads();   // the round barrier
        }
    }
}

extern "C" void kernel_launch(void* const* d_in, const int* in_sizes, int n_in,
                              void* d_out, int out_size, void* d_ws, size_t ws_size,
                              hipStream_t stream) {
    (void)in_sizes; (void)n_in; (void)out_size; (void)d_ws; (void)ws_size;
    const float* x    = (const float*)d_in[0];
    const float* wih0 = (const float*)d_in[1];
    const float* whh0 = (const float*)d_in[2];
    const float* bih0 = (const float*)d_in[3];
    const float* bhh0 = (const float*)d_in[4];
    const float* wih1 = (const float*)d_in[5];
    const float* whh1 = (const float*)d_in[6];
    const float* bih1 = (const float*)d_in[7];
    const float* bhh1 = (const float*)d_in[8];
    const float* wih2 = (const float*)d_in[9];
    const float* whh2 = (const float*)d_in[10];
    const float* bih2 = (const float*)d_in[11];
    const float* bhh2 = (const float*)d_in[12];
    float* out = (float*)d_out;

    rnn_fused<<<dim3(8192 / 32), dim3(512), 0, stream>>>(
        x, wih0, whh0, bih0, bhh0, wih1, whh1, bih1, bhh1,
        wih2, whh2, bih2, bhh2, out);
}

// Round 5
// 555.510 us; speedup vs baseline: 1.5463x; 1.0055x over previous
//
#include <hip/hip_runtime.h>

// ============================================================================
// Fully-fused 3-layer Elman RNN, *** FP32 in/out ***, MFMA 32x32x16 bf16 via
// Ootomo 3-term double-bf16 products (wh*ah + wl*ah + wh*al, err ~2^-18).
//   B=8192, T=64, dims: 84 -> 128 -> 128 -> 84
// R8: 3-role warp specialization -> 3 waves/SIMD.
//   R7 counters: round 13.6k cy, MFMA pipe 4.3k (31%), LDS ~5k, VALU ~4.8k —
//   nothing saturated => latency-bound at 2 waves/SIMD, reg-locked at
//   128 VGPR + 128 AGPR = 256/wave (R5: +32 regs => scratch disaster).
//   Fix: one role per LAYER, 12 waves, __launch_bounds__(768,3) (<=170/wave):
//     L0-role (wv 0-3):  fih0[6]+fhh0[8] = 112 regs; L0 computed fully
//                        (proj+rec in one acc) -> xpF handoff DELETED.
//     L1-role (wv 4-7):  fih1[8]+fhh1[8] = 128 regs (tightest: no staging).
//     L2-role (wv 8-10): fih2[8]+fhh2[6] = 112 regs + out store. SIMDs 0-2.
//     wv 11 (SIMD 3):    staging-only.
//   Pipeline depth 3, 66 rounds, ONE barrier/round; round rr (P=rr&1):
//     L0(t=rr)   reads xb[P], h0[P]  -> h0[PN]     rr in [0,63]
//     L1(t=rr-1) reads h0[P], h1[P]  -> h1[PN]     rr in [1,64]
//     L2(t=rr-2) reads h1[P], h2[P]  -> h2[PN]+out rr in [2,65]
//     stagers:   x(rr+1) issue-early/write-late -> xb[PN]  rr in [0,62]
//   Every producer->consumer gap exactly 1 round (R6/R7 audit shape).
//   Also: staging addresses hoisted (div/mod/64b math once, not per round).
// Numerics: same hi/lo paths; xp now accumulated directly in L0's fp32 acc
// (summation grouping only) -> few-ulp wiggle at most.
// ============================================================================

typedef __bf16 bf16x8 __attribute__((ext_vector_type(8)));
typedef float  f32x4  __attribute__((ext_vector_type(4)));
typedef float  f32x16 __attribute__((ext_vector_type(16)));
typedef unsigned short u16;
typedef unsigned int   u32;
typedef u16 u16x8 __attribute__((ext_vector_type(8)));
typedef u16 u16x4 __attribute__((ext_vector_type(4)));

#define MFMA32(a, b, c) __builtin_amdgcn_mfma_f32_32x32x16_bf16((a), (b), (c), 0, 0, 0)

__device__ __forceinline__ float bf2f(u16 v) {
    return __builtin_bit_cast(float, (u32)v << 16);
}
__device__ __forceinline__ u16 f2bf(float f) {   // RNE, finite inputs
    u32 u = __builtin_bit_cast(u32, f);
    u = u + 0x7fffu + ((u >> 16) & 1u);
    return (u16)(u >> 16);
}
__device__ __forceinline__ float tanh_fast(float x) {
    float xc = fminf(fmaxf(x, -12.f), 12.f);
    float e  = __expf(2.f * xc);
    return (e - 1.f) * __builtin_amdgcn_rcpf(e + 1.f);
}
__device__ __forceinline__ bf16x8 ld_lds8(const u16* p) {
    return __builtin_bit_cast(bf16x8, *(const u16x8*)p);
}
// activation-plane index (u16 units): row stride 128, XOR-swizzled col.
// b128 reads at off mult of 8 (swizzle toggles bits 3..5); b64 writes at col
// mult of 4 stay inside the 16B swizzle cell. (Verified R7.)
__device__ __forceinline__ int aswz(int row, int off) {
    return row * 128 + (off ^ ((row & 7) << 3));
}
// pack 4 floats -> hi/lo bf16 quads, one ds_write_b64 per plane
__device__ __forceinline__ void store4_hl(u16* ph, u16* pl, f32x4 v) {
    u16x4 hi, lo;
#pragma unroll
    for (int j = 0; j < 4; j++) {
        u16 h = f2bf(v[j]);
        hi[j] = h;
        lo[j] = f2bf(v[j] - bf2f(h));
    }
    *(u16x4*)ph = hi;
    *(u16x4*)pl = lo;
}

struct fragp { bf16x8 h, l; };

// Weight A-frag pair, W fp32 row-major [Hr][Kr]; lane holds W[n][kbase..+8)
// split hi/lo. Zero-pads OOB rows/cols. (32x32x16 A-map: row=lane&31,
// k=(lane>>5)*8+j — caller passes n=nb+(lane&31), kbase=c*16+(lane>>5)*8.)
__device__ __forceinline__ fragp load_wfrag_hl(const float* W, int Hr, int Kr,
                                               int n, int kbase) {
    u16x8 uh = {0,0,0,0,0,0,0,0}, ul = {0,0,0,0,0,0,0,0};
    if (n < Hr) {
#pragma unroll
        for (int j = 0; j < 8; j++) {
            int k = kbase + j;
            if (k < Kr) {
                float w = W[n * Kr + k];
                u16 hi = f2bf(w);
                uh[j] = hi;
                ul[j] = f2bf(w - bf2f(hi));
            }
        }
    }
    fragp r;
    r.h = __builtin_bit_cast(bf16x8, uh);
    r.l = __builtin_bit_cast(bf16x8, ul);
    return r;
}

// 3-term double-bf16 accumulate, swapped operands: D += (Wh+Wl)(Ah+Al)
__device__ __forceinline__ f32x16 mm3t(const fragp& w, bf16x8 ah, bf16x8 al, f32x16 c) {
    c = MFMA32(w.h, ah, c);
    c = MFMA32(w.l, ah, c);
    c = MFMA32(w.h, al, c);
    return c;
}

// ---- staging macros (issue-early / write-late, hoisted addresses) ----
// stagers: 512 threads (waves 0-3 and 8-11). j=0..4 always valid
// (max i = 511+2048 = 2559 < 2688); j=5 valid iff tid_s < 128.
#define STG_ISSUE(trr)                                                   \
    {                                                                    \
        const int tofs = (trr) * 84;                                     \
        _Pragma("unroll")                                                \
        for (int j = 0; j < 5; j++) xs[j] = xg[goff[j] + tofs];          \
        if (tid_s < 128) xs[5] = xg[goff[5] + tofs];                     \
    }
#define STG_WRITE(PNv)                                                   \
    {                                                                    \
        u16* bh = (&xbh[0][0][0]) + (PNv) * 3072;                        \
        u16* bl = (&xbl[0][0][0]) + (PNv) * 3072;                        \
        _Pragma("unroll")                                                \
        for (int j = 0; j < 5; j++) {                                    \
            u16 hi = f2bf(xs[j]);                                        \
            bh[lofs[j]] = hi;                                            \
            bl[lofs[j]] = f2bf(xs[j] - bf2f(hi));                        \
        }                                                                \
        if (tid_s < 128) {                                               \
            u16 hi = f2bf(xs[5]);                                        \
            bh[lofs[5]] = hi;                                            \
            bl[lofs[5]] = f2bf(xs[5] - bf2f(hi));                        \
        }                                                                \
    }

__global__ __launch_bounds__(768, 3)  // 12 waves, 3/SIMD: <=170 regs/wave
void rnn_fused(const float* __restrict__ x,
               const float* __restrict__ wih0, const float* __restrict__ whh0,
               const float* __restrict__ bih0, const float* __restrict__ bhh0,
               const float* __restrict__ wih1, const float* __restrict__ whh1,
               const float* __restrict__ bih1, const float* __restrict__ bhh1,
               const float* __restrict__ wih2, const float* __restrict__ whh2,
               const float* __restrict__ bih2, const float* __restrict__ bhh2,
               float* __restrict__ out)
{
    // activation hi/lo planes, [parity][32 rows x 128 cols swizzled] u16
    __shared__ __align__(16) u16 h0h[2][4096], h0l[2][4096];
    __shared__ __align__(16) u16 h1h[2][4096], h1l[2][4096];
    __shared__ __align__(16) u16 h2h[2][4096], h2l[2][4096];
    __shared__ __align__(16) u16 xbh[2][32][96], xbl[2][32][96];  // x_t staging
    __shared__ float biasF[3][128];               // combined biases per layer
    // total LDS: 96K + 24K + 1.5K = 121.5 KiB

    const int tid  = threadIdx.x;
    const int wv   = tid >> 6;        // wave 0..11; SIMD = wv&3
    const int lane = tid & 63;
    const int mrow = lane & 31;       // batch row (D col after operand swap)
    const int q2   = lane >> 5;       // k-half
    const int kq   = q2 * 8;
    const int q4   = q2 * 4;
    const int b0   = blockIdx.x * 32;
    const float* xg = x + (long)b0 * 5376;

    // ---- prologue: zero first-READ parities: L0(0)@rr=0 reads h0[P=0];
    // L1(0)@rr=1 reads h1[P=1]; L2(0)@rr=2 reads h2[P=0].
    { u16* z = &h0h[0][0]; for (int i = tid; i < 4096; i += 768) z[i] = 0; }
    { u16* z = &h0l[0][0]; for (int i = tid; i < 4096; i += 768) z[i] = 0; }
    { u16* z = &h1h[1][0]; for (int i = tid; i < 4096; i += 768) z[i] = 0; }
    { u16* z = &h1l[1][0]; for (int i = tid; i < 4096; i += 768) z[i] = 0; }
    { u16* z = &h2h[0][0]; for (int i = tid; i < 4096; i += 768) z[i] = 0; }
    { u16* z = &h2l[0][0]; for (int i = tid; i < 4096; i += 768) z[i] = 0; }
    // x pad cols 84..95, both parities (written once, stay zero)
    for (int i = tid; i < 32 * 12 * 2; i += 768) {
        int par = i / (32 * 12), rem = i - par * 32 * 12;
        int row = rem / 12, col = 84 + rem - row * 12;
        xbh[par][row][col] = 0; xbl[par][row][col] = 0;
    }
    // stage x(0) -> xb[0]
    for (int i = tid; i < 2688; i += 768) {
        int row = i / 84, col = i - row * 84;
        float v = xg[(long)row * 5376 + col];
        u16 hi = f2bf(v);
        xbh[0][row][col] = hi;
        xbl[0][row][col] = f2bf(v - bf2f(hi));
    }
    // combined biases (pad cols -> 0)
    for (int i = tid; i < 384; i += 768) {
        int l = i >> 7, n = i & 127;
        float v = 0.f;
        if (l == 0)      v = bih0[n] + bhh0[n];
        else if (l == 1) v = bih1[n] + bhh1[n];
        else if (n < 84) v = bih2[n] + bhh2[n];
        biasF[l][n] = v;
    }
    __syncthreads();   // prologue barrier (uniform)

    if (wv < 4) {
        // ================= L0-role: t = rr, rr in [0,63] =================
        const int nb = wv * 32;
        fragp fih0[6], fhh0[8];
#pragma unroll
        for (int c = 0; c < 6; c++)
            fih0[c] = load_wfrag_hl(wih0, 128, 84, nb + mrow, c * 16 + kq);
#pragma unroll
        for (int c = 0; c < 8; c++)
            fhh0[c] = load_wfrag_hl(whh0, 128, 128, nb + mrow, c * 16 + kq);
        // hoisted staging addresses
        const int tid_s = wv * 64 + lane;
        int goff[6], lofs[6];
#pragma unroll
        for (int j = 0; j < 6; j++) {
            int i = tid_s + j * 512, row = i / 84, cc = i - row * 84;
            goff[j] = row * 5376 + cc; lofs[j] = row * 96 + cc;
        }
        float xs[6];

        for (int rr = 0; rr < 66; ++rr) {
            const int P = rr & 1, PN = P ^ 1;
            if (rr <= 62) STG_ISSUE(rr + 1);
            if (rr <= 63) {
                f32x16 acc;
#pragma unroll
                for (int g = 0; g < 4; g++) {
                    f32x4 v = *(const f32x4*)&biasF[0][nb + g * 8 + q4];
                    acc[4*g+0] = v[0]; acc[4*g+1] = v[1];
                    acc[4*g+2] = v[2]; acc[4*g+3] = v[3];
                }
                __builtin_amdgcn_s_setprio(1);
#pragma unroll
                for (int c = 0; c < 6; c++) {      // proj from xb (linear rows)
                    const int off = c * 16 + kq;
                    acc = mm3t(fih0[c], ld_lds8(&xbh[P][mrow][off]),
                                        ld_lds8(&xbl[P][mrow][off]), acc);
                }
#pragma unroll
                for (int c = 0; c < 8; c++) {      // recurrence from h0
                    const int idx = aswz(mrow, c * 16 + kq);
                    acc = mm3t(fhh0[c], ld_lds8(&h0h[P][idx]), ld_lds8(&h0l[P][idx]), acc);
                }
                __builtin_amdgcn_s_setprio(0);
#pragma unroll
                for (int g = 0; g < 4; g++) {
                    const int col = nb + g * 8 + q4;
                    f32x4 v;
                    v[0] = tanh_fast(acc[4*g+0]); v[1] = tanh_fast(acc[4*g+1]);
                    v[2] = tanh_fast(acc[4*g+2]); v[3] = tanh_fast(acc[4*g+3]);
                    const int idx = mrow * 128 + (col ^ ((mrow & 7) << 3));
                    store4_hl(&h0h[PN][idx], &h0l[PN][idx], v);
                }
            }
            if (rr <= 62) STG_WRITE(PN);
            __syncthreads();
        }
    } else if (wv < 8) {
        // ================= L1-role: t = rr-1, rr in [1,64] =================
        const int nb = (wv - 4) * 32;
        fragp fih1[8], fhh1[8];
#pragma unroll
        for (int c = 0; c < 8; c++) {
            fih1[c] = load_wfrag_hl(wih1, 128, 128, nb + mrow, c * 16 + kq);
            fhh1[c] = load_wfrag_hl(whh1, 128, 128, nb + mrow, c * 16 + kq);
        }
        for (int rr = 0; rr < 66; ++rr) {
            const int P = rr & 1, PN = P ^ 1;
            if (rr >= 1 && rr <= 64) {
                f32x16 acc;
#pragma unroll
                for (int g = 0; g < 4; g++) {
                    f32x4 v = *(const f32x4*)&biasF[1][nb + g * 8 + q4];
                    acc[4*g+0] = v[0]; acc[4*g+1] = v[1];
                    acc[4*g+2] = v[2]; acc[4*g+3] = v[3];
                }
                __builtin_amdgcn_s_setprio(1);
#pragma unroll
                for (int c = 0; c < 8; c++) {      // proj from h0
                    const int idx = aswz(mrow, c * 16 + kq);
                    acc = mm3t(fih1[c], ld_lds8(&h0h[P][idx]), ld_lds8(&h0l[P][idx]), acc);
                }
#pragma unroll
                for (int c = 0; c < 8; c++) {      // recurrence from h1
                    const int idx = aswz(mrow, c * 16 + kq);
                    acc = mm3t(fhh1[c], ld_lds8(&h1h[P][idx]), ld_lds8(&h1l[P][idx]), acc);
                }
                __builtin_amdgcn_s_setprio(0);
#pragma unroll
                for (int g = 0; g < 4; g++) {
                    const int col = nb + g * 8 + q4;
                    f32x4 v;
                    v[0] = tanh_fast(acc[4*g+0]); v[1] = tanh_fast(acc[4*g+1]);
                    v[2] = tanh_fast(acc[4*g+2]); v[3] = tanh_fast(acc[4*g+3]);
                    const int idx = mrow * 128 + (col ^ ((mrow & 7) << 3));
                    store4_hl(&h1h[PN][idx], &h1l[PN][idx], v);
                }
            }
            __syncthreads();
        }
    } else if (wv < 11) {
        // ================= L2-role: t = rr-2, rr in [2,65] =================
        const int nb = (wv - 8) * 32;              // cols 0..95 (84 live)
        fragp fih2[8], fhh2[6];
#pragma unroll
        for (int c = 0; c < 8; c++)
            fih2[c] = load_wfrag_hl(wih2, 84, 128, nb + mrow, c * 16 + kq);
#pragma unroll
        for (int c = 0; c < 6; c++)
            fhh2[c] = load_wfrag_hl(whh2, 84, 84, nb + mrow, c * 16 + kq);
        // hoisted staging addresses (stager slots 4,5,6)
        const int tid_s = (wv - 4) * 64 + lane;
        int goff[6], lofs[6];
#pragma unroll
        for (int j = 0; j < 6; j++) {
            int i = tid_s + j * 512, row = i / 84, cc = i - row * 84;
            goff[j] = row * 5376 + cc; lofs[j] = row * 96 + cc;
        }
        float xs[6];

        for (int rr = 0; rr < 66; ++rr) {
            const int P = rr & 1, PN = P ^ 1;
            if (rr <= 62) STG_ISSUE(rr + 1);
            if (rr >= 2) {
                const int t2 = rr - 2;
                f32x16 acc;
#pragma unroll
                for (int g = 0; g < 4; g++) {
                    f32x4 v = *(const f32x4*)&biasF[2][nb + g * 8 + q4];
                    acc[4*g+0] = v[0]; acc[4*g+1] = v[1];
                    acc[4*g+2] = v[2]; acc[4*g+3] = v[3];
                }
                __builtin_amdgcn_s_setprio(1);
#pragma unroll
                for (int c = 0; c < 8; c++) {      // proj from h1
                    const int idx = aswz(mrow, c * 16 + kq);
                    acc = mm3t(fih2[c], ld_lds8(&h1h[P][idx]), ld_lds8(&h1l[P][idx]), acc);
                }
#pragma unroll
                for (int c = 0; c < 6; c++) {      // recurrence from h2
                    const int idx = aswz(mrow, c * 16 + kq);
                    acc = mm3t(fhh2[c], ld_lds8(&h2h[P][idx]), ld_lds8(&h2l[P][idx]), acc);
                }
                __builtin_amdgcn_s_setprio(0);
#pragma unroll
                for (int g = 0; g < 4; g++) {
                    const int col = nb + g * 8 + q4;
                    f32x4 v;
                    v[0] = tanh_fast(acc[4*g+0]); v[1] = tanh_fast(acc[4*g+1]);
                    v[2] = tanh_fast(acc[4*g+2]); v[3] = tanh_fast(acc[4*g+3]);
                    const int idx = mrow * 128 + (col ^ ((mrow & 7) << 3));
                    store4_hl(&h2h[PN][idx], &h2l[PN][idx], v);
                    if (col < 84)   // 84%4==0 -> all-or-nothing per quad
                        *(f32x4*)(out + (long)(b0 + mrow) * 5376 + t2 * 84 + col) = v;
                }
            }
            if (rr <= 62) STG_WRITE(PN);
            __syncthreads();
        }
    } else {
        // ================= wave 11 (SIMD 3): staging-only =================
        const int tid_s = 7 * 64 + lane;
        int goff[6], lofs[6];
#pragma unroll
        for (int j = 0; j < 6; j++) {
            int i = tid_s + j * 512, row = i / 84, cc = i - row * 84;
            goff[j] = row * 5376 + cc; lofs[j] = row * 96 + cc;
        }
        float xs[6];
        for (int rr = 0; rr < 66; ++rr) {
            const int PN = (rr & 1) ^ 1;
            if (rr <= 62) STG_ISSUE(rr + 1);
            if (rr <= 62) STG_WRITE(PN);
            __syncthreads();
        }
    }
}

extern "C" void kernel_launch(void* const* d_in, const int* in_sizes, int n_in,
                              void* d_out, int out_size, void* d_ws, size_t ws_size,
                              hipStream_t stream) {
    (void)in_sizes; (void)n_in; (void)out_size; (void)d_ws; (void)ws_size;
    const float* x    = (const float*)d_in[0];
    const float* wih0 = (const float*)d_in[1];
    const float* whh0 = (const float*)d_in[2];
    const float* bih0 = (const float*)d_in[3];
    const float* bhh0 = (const float*)d_in[4];
    const float* wih1 = (const float*)d_in[5];
    const float* whh1 = (const float*)d_in[6];
    const float* bih1 = (const float*)d_in[7];
    const float* bhh1 = (const float*)d_in[8];
    const float* wih2 = (const float*)d_in[9];
    const float* whh2 = (const float*)d_in[10];
    const float* bih2 = (const float*)d_in[11];
    const float* bhh2 = (const float*)d_in[12];
    float* out = (float*)d_out;

    rnn_fused<<<dim3(8192 / 32), dim3(768), 0, stream>>>(
        x, wih0, whh0, bih0, bhh0, wih1, whh1, bih1, bhh1,
        wih2, whh2, bih2, bhh2, out);
}